// Round 12
// baseline (83.495 us; speedup 1.0000x reference)
//
#include <hip/hip_runtime.h>
#include <hip/hip_bf16.h>
#include <stdint.h>

// ---- types ----
typedef __attribute__((ext_vector_type(4)))  int   i32x4;
typedef __attribute__((ext_vector_type(8)))  int   i32x8;
typedef __attribute__((ext_vector_type(16))) float f32x16;

typedef const void __attribute__((address_space(1)))* gas_ptr;
typedef void __attribute__((address_space(3)))* las_ptr;
#define GLD16(g, l) __builtin_amdgcn_global_load_lds((gas_ptr)(g), (las_ptr)(l), 16, 0, 0)

// ---- problem sizes ----
#define NIMG 32
#define CIN  256
#define HWDIM 56
#define HPAD 58
#define OCH  256
#define SPATIAL (HWDIM*HWDIM)        // 3136
#define M_TOT (NIMG*SPATIAL)         // 100352
#define KTOT  2304                    // 9*256
#define NSTEP 18                      // K-steps of 128 (fp4 nibbles, 64B)
#define ROWB  128                     // bytes per padded spatial position (256c/2)
#define WROWB 1152                    // bytes per o-row of WT4 (2304 nibbles)

// workspace layout (bytes)
#define WT4_OFF   13778944ull         // after xb4: 32*58*58*128
#define ALPHA_OFF 14073856ull         // after WT4: 256*1152

#define LDSBUF 16384                  // [W ks0|W ks1|A ks0|A ks1] x 4KB

// =====================================================================
// Kernel 1: per-o alpha + ternary fp4(e2m1) weights, transposed+packed:
// WT4[o][byte i] = nibbles for k=2i (low), k=2i+1 (high); k = tap*256 + c
// =====================================================================
__global__ __launch_bounds__(256)
void prep_weights(const float* __restrict__ w1, const float* __restrict__ w2,
                  unsigned char* __restrict__ WT4, float* __restrict__ alpha) {
    const int o = blockIdx.x;
    const int t = threadIdx.x;
    const float* p1 = w1 + o * KTOT;
    const float* p2 = w2 + o * KTOT;
    unsigned char* wo = WT4 + o * WROWB;

    float s1 = 0.f, s2 = 0.f;
    for (int i = t; i < WROWB; i += 256) {
        int k0  = 2 * i;
        int tap = k0 >> 8;            // k = tap*256 + c
        int c   = k0 & 255;           // even
        float a0 = p1[c * 9 + tap],       b0 = p2[c * 9 + tap];
        float a1 = p1[(c + 1) * 9 + tap], b1 = p2[(c + 1) * 9 + tap];
        s1 += fabsf(a0) + fabsf(a1);
        s2 += fabsf(b0) + fabsf(b1);
        int sg0 = ((a0 > 0.f) - (a0 < 0.f)) + ((b0 > 0.f) - (b0 < 0.f));
        int sg1 = ((a1 > 0.f) - (a1 < 0.f)) + ((b1 > 0.f) - (b1 < 0.f));
        // fp4 e2m1: +1=0x2 +2=0x4 -1=0xA -2=0xC 0=0x0
        unsigned e0 = (sg0 == 2) ? 0x4u : (sg0 == 1) ? 0x2u : (sg0 == 0) ? 0x0u
                    : (sg0 == -1) ? 0xAu : 0xCu;
        unsigned e1 = (sg1 == 2) ? 0x4u : (sg1 == 1) ? 0x2u : (sg1 == 0) ? 0x0u
                    : (sg1 == -1) ? 0xAu : 0xCu;
        wo[i] = (unsigned char)(e0 | (e1 << 4));
    }
    __shared__ float red[8];
    #pragma unroll
    for (int off = 32; off > 0; off >>= 1) {
        s1 += __shfl_down(s1, off, 64);
        s2 += __shfl_down(s2, off, 64);
    }
    const int lane = t & 63, wv = t >> 6;
    if (lane == 0) { red[wv] = s1; red[4 + wv] = s2; }
    __syncthreads();
    if (t == 0) {
        float t1 = red[0] + red[1] + red[2] + red[3];
        float t2 = red[4] + red[5] + red[6] + red[7];
        alpha[o] = (t1 * (1.f / 2304.f) + t2 * (1.f / 2304.f)) * 0.5f;
    }
}

// =====================================================================
// Kernel 2: binarize x to fp4 nibbles + NCHW -> padded NHWC(/2B), with
// border zeroing. Grid = 32 * 58 blocks: one per (n, hp).
// =====================================================================
__global__ __launch_bounds__(256)
void binarize_kernel(const float* __restrict__ x, unsigned char* __restrict__ xb4) {
    const int b  = blockIdx.x;
    const int n  = b / HPAD;
    const int hp = b % HPAD;
    const int t  = threadIdx.x;
    unsigned char* rowp = xb4 + ((size_t)n * HPAD + hp) * (HPAD * ROWB);

    if (hp == 0 || hp == HPAD - 1) {
        int* ip = (int*)rowp;                 // 58*128 B = 1856 ints
        for (int i = t; i < 1856; i += 256) ip[i] = 0;
        return;
    }
    const int h = hp - 1;
    __shared__ __align__(4) unsigned char tile[HWDIM * 132];  // [w][128B], pad 132
    if (t < 224) {
        const int w  = t % HWDIM;
        const int cl = t / HWDIM;             // 0..3
        const float* xp = x + (size_t)n * (CIN * SPATIAL) + (size_t)h * HWDIM + w;
        for (int c0 = cl * 2; c0 < CIN; c0 += 8) {
            float v0 = xp[(size_t)c0 * SPATIAL];
            float v1 = xp[(size_t)(c0 + 1) * SPATIAL];
            unsigned e0 = (v0 > 0.f) ? 0x2u : ((v0 < 0.f) ? 0xAu : 0x0u);
            unsigned e1 = (v1 > 0.f) ? 0x2u : ((v1 < 0.f) ? 0xAu : 0x0u);
            tile[w * 132 + (c0 >> 1)] = (unsigned char)(e0 | (e1 << 4));
        }
    }
    // zero left/right pad columns of this row
    int* ip = (int*)rowp;
    if (t < 32) ip[t] = 0;                     // w = 0
    else if (t < 64) ip[57 * 32 + (t - 32)] = 0; // w = 57
    __syncthreads();
    // drain: 8 lane-groups of 32; group g writes w = w0+g, 128B coalesced
    const int g = t >> 5, lam = t & 31;
    unsigned char* op = rowp + ROWB;           // w starts at 1
    for (int w0 = 0; w0 < HWDIM; w0 += 8) {
        int w = w0 + g;
        int val = *(const int*)&tile[w * 132 + lam * 4];
        *(int*)(op + (size_t)w * ROWB + lam * 4) = val;
    }
}

// =====================================================================
// Kernel 3: MX-fp4 implicit-GEMM, K=128 steps (18 total). Block = 128(o)
// x 128(sp), 4 waves 2x2, wave = 64x64 (acc[2][2] of 32x32).
// LDS layout per buffer: [W ks0 4KB][W ks1 4KB][A ks0 4KB][A ks1 4KB],
// each sub-area [128 rows][32B]. Staged by DEINTERLEAVING each row's 64B
// chunk into its two ks-halves (source offset ks*32+h*16, linear dest) so
// every MFMA-step wave read is a CONTIGUOUS aligned 1KB span = full 128B
// LDS lines = conflict-free (the r11 1.08e7-conflict fix; half-line reads
// cost ~2x). No swizzle anywhere. Ring-3 (48KB -> 3 blocks/CU),
// homogeneous GLD16 stream, counted vmcnt(4), 1 barrier/step.
// =====================================================================
__global__ __launch_bounds__(256, 3)
void conv_kernel(const unsigned char* __restrict__ xb4,
                 const unsigned char* __restrict__ WT4,
                 const float* __restrict__ alpha,
                 float* __restrict__ out) {
    __shared__ __align__(16) char lds[3 * LDSBUF];

    const int t    = threadIdx.x;
    const int lane = t & 63;
    const int wv   = t >> 6;

    // XCD-aware bijective remap: 1568 blocks = 8 XCDs * 196
    const int bid  = blockIdx.x;
    const int tid_ = (bid & 7) * 196 + (bid >> 3);
    const int nt   = tid_ & 1;        // o-tile (0/1)
    const int mt   = tid_ >> 1;       // sp-tile (0..783)
    const int o0   = nt * 128;
    const int m0   = mt * 128;

    // ---- staging: thread t owns row (t>>1), 16B-half (t&1) of both W and A.
    // Four GLD16s per step: (W ks0, W ks1, A ks0, A ks1), sources at
    // rowbase + step_off + ks*32 + h*16; dests linear t*16 in each 4KB area.
    const int srow = t >> 1;
    const int sh16 = (t & 1) * 16;
    const unsigned char* w_g = WT4 + (size_t)(o0 + srow) * WROWB + sh16;
    const unsigned char* a_g;
    {
        int m  = m0 + srow;
        int ni = m / SPATIAL;
        int sp = m - ni * SPATIAL;
        int h  = sp / HWDIM;
        int w  = sp - h * HWDIM;
        a_g = xb4 + ((size_t)(ni * HPAD + h) * HPAD + w) * ROWB + sh16;
    }
    char* dstT = lds + t * 16;

    f32x16 acc[2][2];
    #pragma unroll
    for (int i = 0; i < 2; ++i)
        #pragma unroll
        for (int j = 0; j < 2; ++j)
            acc[i][j] = (f32x16){0.f,0.f,0.f,0.f,0.f,0.f,0.f,0.f,
                                 0.f,0.f,0.f,0.f,0.f,0.f,0.f,0.f};

    // ---- read-side: lane (row l31, 16B-half l5); contiguous per instr ----
    const int l31 = lane & 31;
    const int l5  = lane >> 5;
    const int wro = ((wv & 1) * 64 + l31) * 32 + l5 * 16;          // in W area
    const int aro = 8192 + ((wv >> 1) * 64 + l31) * 32 + l5 * 16;  // in A area

    // STAGE step S: tap = S>>1, ch = (S&1)*64 (which 64B half of the row)
    #define STAGE(S, B)                                                     \
    {                                                                       \
        const int s_ = (S);                                                 \
        const int tap = s_ >> 1;                                            \
        const int kh = tap / 3, kw = tap - kh * 3;                          \
        const int ch = (s_ & 1) * 64;                                       \
        const int aoff = (kh * HPAD + kw) * ROWB + ch;                      \
        const int woff = tap * 128 + ch;                                    \
        char* d = dstT + (B) * LDSBUF;                                      \
        GLD16(w_g + woff,      d);                                          \
        GLD16(w_g + woff + 32, d + 4096);                                   \
        GLD16(a_g + aoff,      d + 8192);                                   \
        GLD16(a_g + aoff + 32, d + 12288);                                  \
    }

    i32x8 wf[2] = {};
    i32x8 xf[2] = {};

    // prologue: stage 0,1 (8 loads); wait stage 0 (4 younger); barrier
    STAGE(0, 0);
    STAGE(1, 1);
    asm volatile("s_waitcnt vmcnt(4)\n\ts_barrier" ::: "memory");

    #pragma unroll
    for (int s = 0; s < NSTEP; ++s) {
        const char* Wb = lds + (s % 3) * LDSBUF;

        if (s + 2 < NSTEP) STAGE(s + 2, (s + 2) % 3);   // 4 DMA

        #pragma unroll
        for (int ks = 0; ks < 2; ++ks) {
            const char* Kb = Wb + ks * 4096;
            *(i32x4*)&wf[0] = *(const i32x4*)(Kb + wro);
            *(i32x4*)&wf[1] = *(const i32x4*)(Kb + wro + 1024);
            *(i32x4*)&xf[0] = *(const i32x4*)(Kb + aro);
            *(i32x4*)&xf[1] = *(const i32x4*)(Kb + aro + 1024);

            __builtin_amdgcn_s_setprio(1);
            #pragma unroll
            for (int i = 0; i < 2; ++i)
                #pragma unroll
                for (int j = 0; j < 2; ++j)
                    acc[i][j] = __builtin_amdgcn_mfma_scale_f32_32x32x64_f8f6f4(
                        wf[i], xf[j], acc[i][j], 4, 4, 0, 127, 0, 127);
            __builtin_amdgcn_s_setprio(0);
        }

        // end-of-step: stage s+1 retired (4 younger DMA), reads drained, barrier
        if (s < NSTEP - 2)
            asm volatile("s_waitcnt vmcnt(4) lgkmcnt(0)\n\ts_barrier" ::: "memory");
        else if (s == NSTEP - 2)
            asm volatile("s_waitcnt vmcnt(0) lgkmcnt(0)\n\ts_barrier" ::: "memory");
    }

    // ---- epilogue: out[n][o][h][w] = acc * alpha[o] ----
    // 32x32 D frag: col(sp) = lane&31, row(o) = (reg&3)+8*(reg>>2)+4*(lane>>5)
    const int ob0 = o0 + (wv & 1) * 64;
    const int mb0 = m0 + (wv >> 1) * 64;
    #pragma unroll
    for (int j = 0; j < 2; ++j) {
        int m  = mb0 + j * 32 + l31;
        int ni = m / SPATIAL;
        int sp = m - ni * SPATIAL;
        long base = (long)ni * (OCH * SPATIAL) + sp;
        #pragma unroll
        for (int i = 0; i < 2; ++i) {
            #pragma unroll
            for (int r = 0; r < 16; ++r) {
                int o = ob0 + i * 32 + (r & 3) + 8 * (r >> 2) + 4 * l5;
                out[base + (long)o * SPATIAL] = acc[i][j][r] * alpha[o];
            }
        }
    }
    #undef STAGE
}

// =====================================================================
extern "C" void kernel_launch(void* const* d_in, const int* in_sizes, int n_in,
                              void* d_out, int out_size, void* d_ws, size_t ws_size,
                              hipStream_t stream) {
    const float* x  = (const float*)d_in[0];
    const float* w1 = (const float*)d_in[1];
    const float* w2 = (const float*)d_in[2];
    float* out = (float*)d_out;

    char* ws = (char*)d_ws;
    unsigned char* xb4   = (unsigned char*)ws;
    unsigned char* WT4   = (unsigned char*)(ws + WT4_OFF);
    float*         alpha = (float*)(ws + ALPHA_OFF);

    hipLaunchKernelGGL(prep_weights, dim3(OCH), dim3(256), 0, stream, w1, w2, WT4, alpha);
    hipLaunchKernelGGL(binarize_kernel, dim3(NIMG * HPAD), dim3(256), 0, stream, x, xb4);
    hipLaunchKernelGGL(conv_kernel, dim3((M_TOT / 128) * 2), dim3(256), 0, stream,
                       xb4, WT4, alpha, out);
}

// Round 13
// 82.454 us; speedup vs baseline: 1.0126x; 1.0126x over previous
//
#include <hip/hip_runtime.h>
#include <hip/hip_bf16.h>
#include <stdint.h>

// ---- types ----
typedef __attribute__((ext_vector_type(4)))  int   i32x4;
typedef __attribute__((ext_vector_type(8)))  int   i32x8;
typedef __attribute__((ext_vector_type(16))) float f32x16;

typedef const void __attribute__((address_space(1)))* gas_ptr;
typedef void __attribute__((address_space(3)))* las_ptr;
#define GLD16(g, l) __builtin_amdgcn_global_load_lds((gas_ptr)(g), (las_ptr)(l), 16, 0, 0)

// ---- problem sizes ----
#define NIMG 32
#define CIN  256
#define HWDIM 56
#define HPAD 58
#define OCH  256
#define SPATIAL (HWDIM*HWDIM)        // 3136
#define M_TOT (NIMG*SPATIAL)         // 100352
#define KTOT  2304                    // 9*256
#define NSTEP 18                      // K-steps of 128 (fp4 nibbles, 64B)
#define ROWB  128                     // bytes per padded spatial position (256c/2)
#define WROWB 1152                    // bytes per o-row of WT4 (2304 nibbles)

// workspace layout (bytes)
#define WT4_OFF   13778944ull         // after xb4: 32*58*58*128
#define ALPHA_OFF 14073856ull         // after WT4: 256*1152

#define LDSBUF 16384                  // [W ks0|W ks1|A ks0|A ks1] x 4KB

// =====================================================================
// Kernel 1: per-o alpha + ternary fp4(e2m1) weights, transposed+packed:
// WT4[o][byte i] = nibbles for k=2i (low), k=2i+1 (high); k = tap*256 + c
// =====================================================================
__global__ __launch_bounds__(256)
void prep_weights(const float* __restrict__ w1, const float* __restrict__ w2,
                  unsigned char* __restrict__ WT4, float* __restrict__ alpha) {
    const int o = blockIdx.x;
    const int t = threadIdx.x;
    const float* p1 = w1 + o * KTOT;
    const float* p2 = w2 + o * KTOT;
    unsigned char* wo = WT4 + o * WROWB;

    float s1 = 0.f, s2 = 0.f;
    for (int i = t; i < WROWB; i += 256) {
        int k0  = 2 * i;
        int tap = k0 >> 8;            // k = tap*256 + c
        int c   = k0 & 255;           // even
        float a0 = p1[c * 9 + tap],       b0 = p2[c * 9 + tap];
        float a1 = p1[(c + 1) * 9 + tap], b1 = p2[(c + 1) * 9 + tap];
        s1 += fabsf(a0) + fabsf(a1);
        s2 += fabsf(b0) + fabsf(b1);
        int sg0 = ((a0 > 0.f) - (a0 < 0.f)) + ((b0 > 0.f) - (b0 < 0.f));
        int sg1 = ((a1 > 0.f) - (a1 < 0.f)) + ((b1 > 0.f) - (b1 < 0.f));
        // fp4 e2m1: +1=0x2 +2=0x4 -1=0xA -2=0xC 0=0x0
        unsigned e0 = (sg0 == 2) ? 0x4u : (sg0 == 1) ? 0x2u : (sg0 == 0) ? 0x0u
                    : (sg0 == -1) ? 0xAu : 0xCu;
        unsigned e1 = (sg1 == 2) ? 0x4u : (sg1 == 1) ? 0x2u : (sg1 == 0) ? 0x0u
                    : (sg1 == -1) ? 0xAu : 0xCu;
        wo[i] = (unsigned char)(e0 | (e1 << 4));
    }
    __shared__ float red[8];
    #pragma unroll
    for (int off = 32; off > 0; off >>= 1) {
        s1 += __shfl_down(s1, off, 64);
        s2 += __shfl_down(s2, off, 64);
    }
    const int lane = t & 63, wv = t >> 6;
    if (lane == 0) { red[wv] = s1; red[4 + wv] = s2; }
    __syncthreads();
    if (t == 0) {
        float t1 = red[0] + red[1] + red[2] + red[3];
        float t2 = red[4] + red[5] + red[6] + red[7];
        alpha[o] = (t1 * (1.f / 2304.f) + t2 * (1.f / 2304.f)) * 0.5f;
    }
}

// =====================================================================
// Kernel 2: binarize x to fp4 nibbles + NCHW -> padded NHWC(/2B), with
// border zeroing. Grid = 32 * 58 blocks: one per (n, hp).
// =====================================================================
__global__ __launch_bounds__(256)
void binarize_kernel(const float* __restrict__ x, unsigned char* __restrict__ xb4) {
    const int b  = blockIdx.x;
    const int n  = b / HPAD;
    const int hp = b % HPAD;
    const int t  = threadIdx.x;
    unsigned char* rowp = xb4 + ((size_t)n * HPAD + hp) * (HPAD * ROWB);

    if (hp == 0 || hp == HPAD - 1) {
        int* ip = (int*)rowp;                 // 58*128 B = 1856 ints
        for (int i = t; i < 1856; i += 256) ip[i] = 0;
        return;
    }
    const int h = hp - 1;
    __shared__ __align__(4) unsigned char tile[HWDIM * 132];  // [w][128B], pad 132
    if (t < 224) {
        const int w  = t % HWDIM;
        const int cl = t / HWDIM;             // 0..3
        const float* xp = x + (size_t)n * (CIN * SPATIAL) + (size_t)h * HWDIM + w;
        for (int c0 = cl * 2; c0 < CIN; c0 += 8) {
            float v0 = xp[(size_t)c0 * SPATIAL];
            float v1 = xp[(size_t)(c0 + 1) * SPATIAL];
            unsigned e0 = (v0 > 0.f) ? 0x2u : ((v0 < 0.f) ? 0xAu : 0x0u);
            unsigned e1 = (v1 > 0.f) ? 0x2u : ((v1 < 0.f) ? 0xAu : 0x0u);
            tile[w * 132 + (c0 >> 1)] = (unsigned char)(e0 | (e1 << 4));
        }
    }
    // zero left/right pad columns of this row
    int* ip = (int*)rowp;
    if (t < 32) ip[t] = 0;                     // w = 0
    else if (t < 64) ip[57 * 32 + (t - 32)] = 0; // w = 57
    __syncthreads();
    // drain: 8 lane-groups of 32; group g writes w = w0+g, 128B coalesced
    const int g = t >> 5, lam = t & 31;
    unsigned char* op = rowp + ROWB;           // w starts at 1
    for (int w0 = 0; w0 < HWDIM; w0 += 8) {
        int w = w0 + g;
        int val = *(const int*)&tile[w * 132 + lam * 4];
        *(int*)(op + (size_t)w * ROWB + lam * 4) = val;
    }
}

// =====================================================================
// Kernel 3: MX-fp4 implicit-GEMM, K=128 steps (18 total). Block = 128(o)
// x 128(sp), 4 waves 2x2, wave = 64x64 (acc[2][2] of 32x32).
// RING-4 + DEPTH-3 PREFETCH (the r3 sync skeleton): stage s+3 at step s,
// end-of-step wait vmcnt(8) lgkmcnt(0) -> stage s+1 complete, 2 stages in
// flight across the barrier. Rationale: cross-round regression r3-r12
// shows wall-step = max(~1.8k cyc issue, DMA-latency/depth); depth-1
// schemes all sat at ~3.5k cyc (global_load_lds round-trip ~3.5k), r3's
// depth-3 ran 1.86k. LDS layout/staging byte-identical to r12 (passed):
// per buffer [W ks0|W ks1|A ks0|A ks1] x 4KB, deinterleaved ks-halves,
// contiguous 1KB wave reads. No setprio. Ring-4 = 64KB -> 2 blocks/CU.
// =====================================================================
__global__ __launch_bounds__(256, 2)
void conv_kernel(const unsigned char* __restrict__ xb4,
                 const unsigned char* __restrict__ WT4,
                 const float* __restrict__ alpha,
                 float* __restrict__ out) {
    __shared__ __align__(16) char lds[4 * LDSBUF];

    const int t    = threadIdx.x;
    const int lane = t & 63;
    const int wv   = t >> 6;

    // XCD-aware bijective remap: 1568 blocks = 8 XCDs * 196
    const int bid  = blockIdx.x;
    const int tid_ = (bid & 7) * 196 + (bid >> 3);
    const int nt   = tid_ & 1;        // o-tile (0/1)
    const int mt   = tid_ >> 1;       // sp-tile (0..783)
    const int o0   = nt * 128;
    const int m0   = mt * 128;

    // ---- staging: thread t owns row (t>>1), 16B-half (t&1) of both W and A.
    // Four GLD16s per step: (W ks0, W ks1, A ks0, A ks1), sources at
    // rowbase + step_off + ks*32 + h*16; dests linear t*16 in each 4KB area.
    const int srow = t >> 1;
    const int sh16 = (t & 1) * 16;
    const unsigned char* w_g = WT4 + (size_t)(o0 + srow) * WROWB + sh16;
    const unsigned char* a_g;
    {
        int m  = m0 + srow;
        int ni = m / SPATIAL;
        int sp = m - ni * SPATIAL;
        int h  = sp / HWDIM;
        int w  = sp - h * HWDIM;
        a_g = xb4 + ((size_t)(ni * HPAD + h) * HPAD + w) * ROWB + sh16;
    }
    char* dstT = lds + t * 16;

    f32x16 acc[2][2];
    #pragma unroll
    for (int i = 0; i < 2; ++i)
        #pragma unroll
        for (int j = 0; j < 2; ++j)
            acc[i][j] = (f32x16){0.f,0.f,0.f,0.f,0.f,0.f,0.f,0.f,
                                 0.f,0.f,0.f,0.f,0.f,0.f,0.f,0.f};

    // ---- read-side: lane (row l31, 16B-half l5); contiguous per instr ----
    const int l31 = lane & 31;
    const int l5  = lane >> 5;
    const int wro = ((wv & 1) * 64 + l31) * 32 + l5 * 16;          // in W area
    const int aro = 8192 + ((wv >> 1) * 64 + l31) * 32 + l5 * 16;  // in A area

    // STAGE step S: tap = S>>1, ch = (S&1)*64 (which 64B half of the row)
    #define STAGE(S, B)                                                     \
    {                                                                       \
        const int s_ = (S);                                                 \
        const int tap = s_ >> 1;                                            \
        const int kh = tap / 3, kw = tap - kh * 3;                          \
        const int ch = (s_ & 1) * 64;                                       \
        const int aoff = (kh * HPAD + kw) * ROWB + ch;                      \
        const int woff = tap * 128 + ch;                                    \
        char* d = dstT + (B) * LDSBUF;                                      \
        GLD16(w_g + woff,      d);                                          \
        GLD16(w_g + woff + 32, d + 4096);                                   \
        GLD16(a_g + aoff,      d + 8192);                                   \
        GLD16(a_g + aoff + 32, d + 12288);                                  \
    }

    i32x8 wf[2] = {};
    i32x8 xf[2] = {};

    // prologue: stage 0,1,2 (12 loads); wait stage 0 (8 younger); barrier
    STAGE(0, 0);
    STAGE(1, 1);
    STAGE(2, 2);
    asm volatile("s_waitcnt vmcnt(8)\n\ts_barrier" ::: "memory");

    #pragma unroll
    for (int s = 0; s < NSTEP; ++s) {
        const char* Wb = lds + (s & 3) * LDSBUF;

        if (s + 3 < NSTEP) STAGE(s + 3, (s + 3) & 3);   // depth-3 prefetch

        #pragma unroll
        for (int ks = 0; ks < 2; ++ks) {
            const char* Kb = Wb + ks * 4096;
            *(i32x4*)&wf[0] = *(const i32x4*)(Kb + wro);
            *(i32x4*)&wf[1] = *(const i32x4*)(Kb + wro + 1024);
            *(i32x4*)&xf[0] = *(const i32x4*)(Kb + aro);
            *(i32x4*)&xf[1] = *(const i32x4*)(Kb + aro + 1024);

            #pragma unroll
            for (int i = 0; i < 2; ++i)
                #pragma unroll
                for (int j = 0; j < 2; ++j)
                    acc[i][j] = __builtin_amdgcn_mfma_scale_f32_32x32x64_f8f6f4(
                        wf[i], xf[j], acc[i][j], 4, 4, 0, 127, 0, 127);
        }

        // end-of-step: stage s+1 retired; 2 stages (8 DMA) stay in flight
        if (s <= NSTEP - 4)
            asm volatile("s_waitcnt vmcnt(8) lgkmcnt(0)\n\ts_barrier" ::: "memory");
        else if (s == NSTEP - 3)
            asm volatile("s_waitcnt vmcnt(4) lgkmcnt(0)\n\ts_barrier" ::: "memory");
        else if (s == NSTEP - 2)
            asm volatile("s_waitcnt vmcnt(0) lgkmcnt(0)\n\ts_barrier" ::: "memory");
    }

    // ---- epilogue: out[n][o][h][w] = acc * alpha[o] ----
    // 32x32 D frag: col(sp) = lane&31, row(o) = (reg&3)+8*(reg>>2)+4*(lane>>5)
    const int ob0 = o0 + (wv & 1) * 64;
    const int mb0 = m0 + (wv >> 1) * 64;
    #pragma unroll
    for (int j = 0; j < 2; ++j) {
        int m  = mb0 + j * 32 + l31;
        int ni = m / SPATIAL;
        int sp = m - ni * SPATIAL;
        long base = (long)ni * (OCH * SPATIAL) + sp;
        #pragma unroll
        for (int i = 0; i < 2; ++i) {
            #pragma unroll
            for (int r = 0; r < 16; ++r) {
                int o = ob0 + i * 32 + (r & 3) + 8 * (r >> 2) + 4 * l5;
                out[base + (long)o * SPATIAL] = acc[i][j][r] * alpha[o];
            }
        }
    }
    #undef STAGE
}

// =====================================================================
extern "C" void kernel_launch(void* const* d_in, const int* in_sizes, int n_in,
                              void* d_out, int out_size, void* d_ws, size_t ws_size,
                              hipStream_t stream) {
    const float* x  = (const float*)d_in[0];
    const float* w1 = (const float*)d_in[1];
    const float* w2 = (const float*)d_in[2];
    float* out = (float*)d_out;

    char* ws = (char*)d_ws;
    unsigned char* xb4   = (unsigned char*)ws;
    unsigned char* WT4   = (unsigned char*)(ws + WT4_OFF);
    float*         alpha = (float*)(ws + ALPHA_OFF);

    hipLaunchKernelGGL(prep_weights, dim3(OCH), dim3(256), 0, stream, w1, w2, WT4, alpha);
    hipLaunchKernelGGL(binarize_kernel, dim3(NIMG * HPAD), dim3(256), 0, stream, x, xb4);
    hipLaunchKernelGGL(conv_kernel, dim3((M_TOT / 128) * 2), dim3(256), 0, stream,
                       xb4, WT4, alpha, out);
}

// Round 14
// 72.006 us; speedup vs baseline: 1.1596x; 1.1451x over previous
//
#include <hip/hip_runtime.h>
#include <hip/hip_bf16.h>
#include <stdint.h>

// ---- types ----
typedef __attribute__((ext_vector_type(4)))  int   i32x4;
typedef __attribute__((ext_vector_type(8)))  int   i32x8;
typedef __attribute__((ext_vector_type(16))) float f32x16;

typedef const void __attribute__((address_space(1)))* gas_ptr;
typedef void __attribute__((address_space(3)))* las_ptr;
#define GLD16(g, l) __builtin_amdgcn_global_load_lds((gas_ptr)(g), (las_ptr)(l), 16, 0, 0)

// ---- problem sizes ----
#define NIMG 32
#define CIN  256
#define HWDIM 56
#define HPAD 58
#define OCH  256
#define SPATIAL (HWDIM*HWDIM)        // 3136
#define M_TOT (NIMG*SPATIAL)         // 100352
#define KTOT  2304                    // 9*256
#define NSTEP 9                       // K-steps of 256 nibbles = one tap = 128B
#define ROWB  128                     // bytes per padded spatial position (256c/2)

// workspace layout (bytes)
#define WT4_OFF   13778944ull         // after xb4: 32*58*58*128
#define ALPHA_OFF 14073856ull         // after WT4R: 9*256*128 = 294912

#define LDSBUF 32768                  // [W 128x128B][A 128x128B]

// =====================================================================
// Kernel 1: per-o alpha + ternary fp4(e2m1) weights, packed to
// WT4R[tap][o][128B]: byte i of (tap,o) = nibbles k=tap*256+2i | 2i+1.
// =====================================================================
__global__ __launch_bounds__(256)
void prep_weights(const float* __restrict__ w1, const float* __restrict__ w2,
                  unsigned char* __restrict__ WT4R, float* __restrict__ alpha) {
    const int o = blockIdx.x;
    const int t = threadIdx.x;
    const float* p1 = w1 + o * KTOT;
    const float* p2 = w2 + o * KTOT;

    float s1 = 0.f, s2 = 0.f;
    for (int i = t; i < 1152; i += 256) {
        int k0  = 2 * i;
        int tap = k0 >> 8;            // k = tap*256 + c
        int c   = k0 & 255;           // even
        float a0 = p1[c * 9 + tap],       b0 = p2[c * 9 + tap];
        float a1 = p1[(c + 1) * 9 + tap], b1 = p2[(c + 1) * 9 + tap];
        s1 += fabsf(a0) + fabsf(a1);
        s2 += fabsf(b0) + fabsf(b1);
        int sg0 = ((a0 > 0.f) - (a0 < 0.f)) + ((b0 > 0.f) - (b0 < 0.f));
        int sg1 = ((a1 > 0.f) - (a1 < 0.f)) + ((b1 > 0.f) - (b1 < 0.f));
        // fp4 e2m1: +1=0x2 +2=0x4 -1=0xA -2=0xC 0=0x0
        unsigned e0 = (sg0 == 2) ? 0x4u : (sg0 == 1) ? 0x2u : (sg0 == 0) ? 0x0u
                    : (sg0 == -1) ? 0xAu : 0xCu;
        unsigned e1 = (sg1 == 2) ? 0x4u : (sg1 == 1) ? 0x2u : (sg1 == 0) ? 0x0u
                    : (sg1 == -1) ? 0xAu : 0xCu;
        WT4R[(size_t)tap * (OCH * ROWB) + o * ROWB + (i & 127)] =
            (unsigned char)(e0 | (e1 << 4));
    }
    __shared__ float red[8];
    #pragma unroll
    for (int off = 32; off > 0; off >>= 1) {
        s1 += __shfl_down(s1, off, 64);
        s2 += __shfl_down(s2, off, 64);
    }
    const int lane = t & 63, wv = t >> 6;
    if (lane == 0) { red[wv] = s1; red[4 + wv] = s2; }
    __syncthreads();
    if (t == 0) {
        float t1 = red[0] + red[1] + red[2] + red[3];
        float t2 = red[4] + red[5] + red[6] + red[7];
        alpha[o] = (t1 * (1.f / 2304.f) + t2 * (1.f / 2304.f)) * 0.5f;
    }
}

// =====================================================================
// Kernel 2: binarize x to fp4 nibbles + NCHW -> padded NHWC(/2B), with
// border zeroing. Grid = 32 * 58 blocks: one per (n, hp).
// =====================================================================
__global__ __launch_bounds__(256)
void binarize_kernel(const float* __restrict__ x, unsigned char* __restrict__ xb4) {
    const int b  = blockIdx.x;
    const int n  = b / HPAD;
    const int hp = b % HPAD;
    const int t  = threadIdx.x;
    unsigned char* rowp = xb4 + ((size_t)n * HPAD + hp) * (HPAD * ROWB);

    if (hp == 0 || hp == HPAD - 1) {
        int* ip = (int*)rowp;                 // 58*128 B = 1856 ints
        for (int i = t; i < 1856; i += 256) ip[i] = 0;
        return;
    }
    const int h = hp - 1;
    __shared__ __align__(4) unsigned char tile[HWDIM * 132];  // [w][128B], pad 132
    if (t < 224) {
        const int w  = t % HWDIM;
        const int cl = t / HWDIM;             // 0..3
        const float* xp = x + (size_t)n * (CIN * SPATIAL) + (size_t)h * HWDIM + w;
        for (int c0 = cl * 2; c0 < CIN; c0 += 8) {
            float v0 = xp[(size_t)c0 * SPATIAL];
            float v1 = xp[(size_t)(c0 + 1) * SPATIAL];
            unsigned e0 = (v0 > 0.f) ? 0x2u : ((v0 < 0.f) ? 0xAu : 0x0u);
            unsigned e1 = (v1 > 0.f) ? 0x2u : ((v1 < 0.f) ? 0xAu : 0x0u);
            tile[w * 132 + (c0 >> 1)] = (unsigned char)(e0 | (e1 << 4));
        }
    }
    // zero left/right pad columns of this row
    int* ip = (int*)rowp;
    if (t < 32) ip[t] = 0;                     // w = 0
    else if (t < 64) ip[57 * 32 + (t - 32)] = 0; // w = 57
    __syncthreads();
    // drain: 8 lane-groups of 32; group g writes w = w0+g, 128B coalesced
    const int g = t >> 5, lam = t & 31;
    unsigned char* op = rowp + ROWB;           // w starts at 1
    for (int w0 = 0; w0 < HWDIM; w0 += 8) {
        int w = w0 + g;
        int val = *(const int*)&tile[w * 132 + lam * 4];
        *(int*)(op + (size_t)w * ROWB + lam * 4) = val;
    }
}

// =====================================================================
// Kernel 3: MX-fp4 implicit-GEMM, K-step = 256 nibbles = ONE TAP (9 steps).
// Block = 128(o) x 128(sp), 4 waves 2x2, wave = 64x64 (acc[2][2] of 32x32).
// CONTIGUOUS staging: W block [tap][o][128B] = 16KB dense; A = full 128B
// position-rows, consecutive positions consecutive in memory -> every
// GLD16 wave-instr reads a dense 1KB span (vs r11-r13's 32-segment
// gathers; same instr count, ~4x fewer TA segments). LDS rows of 128B
// XOR-swizzled chunk' = chunk ^ (row&7), BOTH sides: pre-swizzled global
// source (permutation stays within each row's 128B -> lines stay dense)
// + swizzled ds_read = exactly 8 accesses/bank (b128 minimum, conflict-
// free). Ring-2 (64KB -> 2 blocks/CU), 9 barriers, vmcnt(0)+lgkm per step
// (issue->wait covered by the 4-ks compute + 2-block co-residency).
// =====================================================================
__global__ __launch_bounds__(256, 2)
void conv_kernel(const unsigned char* __restrict__ xb4,
                 const unsigned char* __restrict__ WT4R,
                 const float* __restrict__ alpha,
                 float* __restrict__ out) {
    __shared__ __align__(16) char lds[2 * LDSBUF];

    const int t    = threadIdx.x;
    const int lane = t & 63;
    const int wv   = t >> 6;

    // XCD-aware bijective remap: 1568 blocks = 8 XCDs * 196
    const int bid  = blockIdx.x;
    const int tid_ = (bid & 7) * 196 + (bid >> 3);
    const int nt   = tid_ & 1;        // o-tile (0/1)
    const int mt   = tid_ >> 1;       // sp-tile (0..783)
    const int o0   = nt * 128;
    const int m0   = mt * 128;

    // ---- staging: thread t owns row (t>>3)+q*32, chunk t&7 (16B) of each
    // area; source chunk pre-swizzled: sx = (t&7) ^ ((t>>3)&7).
    const int sr = t >> 3;
    const int sx = ((t & 7) ^ (sr & 7)) * 16;
    const unsigned char* w_g[4];
    const unsigned char* a_g[4];
    #pragma unroll
    for (int q = 0; q < 4; ++q) {
        w_g[q] = WT4R + (size_t)(o0 + sr + q * 32) * ROWB + sx;
        int m  = m0 + sr + q * 32;
        int ni = m / SPATIAL;
        int sp = m - ni * SPATIAL;
        int h  = sp / HWDIM;
        int w  = sp - h * HWDIM;
        a_g[q] = xb4 + ((size_t)(ni * HPAD + h) * HPAD + w) * ROWB + sx;
    }
    char* dstT = lds + t * 16;

    f32x16 acc[2][2];
    #pragma unroll
    for (int i = 0; i < 2; ++i)
        #pragma unroll
        for (int j = 0; j < 2; ++j)
            acc[i][j] = (f32x16){0.f,0.f,0.f,0.f,0.f,0.f,0.f,0.f,
                                 0.f,0.f,0.f,0.f,0.f,0.f,0.f,0.f};

    // ---- read-side: lane (row l31, 16B-half l5); swizzled chunk per ks ----
    const int l31 = lane & 31;
    const int l5  = lane >> 5;
    const int r7  = l31 & 7;
    const int wr0 = ((wv & 1) * 64 + l31) * ROWB;            // W row i=0
    const int ar0 = 16384 + (((wv >> 1) * 64) + l31) * ROWB; // A row j=0

    // STAGE step S (= tap) into buffer B: 8 dense-1KB GLD16
    #define STAGE(S, B)                                                     \
    {                                                                       \
        const int tap = (S);                                                \
        const int kh = tap / 3, kw = tap - kh * 3;                          \
        const int aoff = (kh * HPAD + kw) * ROWB;                           \
        const int woff = tap * (OCH * ROWB);                                \
        char* d = dstT + (B) * LDSBUF;                                      \
        GLD16(w_g[0] + woff, d);                                            \
        GLD16(w_g[1] + woff, d + 4096);                                     \
        GLD16(w_g[2] + woff, d + 8192);                                     \
        GLD16(w_g[3] + woff, d + 12288);                                    \
        GLD16(a_g[0] + aoff, d + 16384);                                    \
        GLD16(a_g[1] + aoff, d + 20480);                                    \
        GLD16(a_g[2] + aoff, d + 24576);                                    \
        GLD16(a_g[3] + aoff, d + 28672);                                    \
    }

    // prologue: stage 0; drain; barrier
    STAGE(0, 0);
    asm volatile("s_waitcnt vmcnt(0)\n\ts_barrier" ::: "memory");

    #pragma unroll
    for (int s = 0; s < NSTEP; ++s) {
        const char* Wb = lds + (s & 1) * LDSBUF;

        if (s + 1 < NSTEP) STAGE(s + 1, (s + 1) & 1);

        #pragma unroll
        for (int ks = 0; ks < 4; ++ks) {
            const int off = (((ks << 1) | l5) ^ r7) << 4;   // swizzled chunk
            i32x8 wf[2] = {};
            i32x8 xf[2] = {};
            *(i32x4*)&wf[0] = *(const i32x4*)(Wb + wr0 + off);
            *(i32x4*)&wf[1] = *(const i32x4*)(Wb + wr0 + 32 * ROWB + off);
            *(i32x4*)&xf[0] = *(const i32x4*)(Wb + ar0 + off);
            *(i32x4*)&xf[1] = *(const i32x4*)(Wb + ar0 + 32 * ROWB + off);

            #pragma unroll
            for (int i = 0; i < 2; ++i)
                #pragma unroll
                for (int j = 0; j < 2; ++j)
                    acc[i][j] = __builtin_amdgcn_mfma_scale_f32_32x32x64_f8f6f4(
                        wf[i], xf[j], acc[i][j], 4, 4, 0, 127, 0, 127);
        }

        // end-of-step: next stage complete, reads drained, barrier
        if (s + 1 < NSTEP)
            asm volatile("s_waitcnt vmcnt(0) lgkmcnt(0)\n\ts_barrier" ::: "memory");
    }

    // ---- epilogue: out[n][o][h][w] = acc * alpha[o] ----
    // 32x32 D frag: col(sp) = lane&31, row(o) = (reg&3)+8*(reg>>2)+4*(lane>>5)
    const int ob0 = o0 + (wv & 1) * 64;
    const int mb0 = m0 + (wv >> 1) * 64;
    #pragma unroll
    for (int j = 0; j < 2; ++j) {
        int m  = mb0 + j * 32 + l31;
        int ni = m / SPATIAL;
        int sp = m - ni * SPATIAL;
        long base = (long)ni * (OCH * SPATIAL) + sp;
        #pragma unroll
        for (int i = 0; i < 2; ++i) {
            #pragma unroll
            for (int r = 0; r < 16; ++r) {
                int o = ob0 + i * 32 + (r & 3) + 8 * (r >> 2) + 4 * l5;
                out[base + (long)o * SPATIAL] = acc[i][j][r] * alpha[o];
            }
        }
    }
    #undef STAGE
}

// =====================================================================
extern "C" void kernel_launch(void* const* d_in, const int* in_sizes, int n_in,
                              void* d_out, int out_size, void* d_ws, size_t ws_size,
                              hipStream_t stream) {
    const float* x  = (const float*)d_in[0];
    const float* w1 = (const float*)d_in[1];
    const float* w2 = (const float*)d_in[2];
    float* out = (float*)d_out;

    char* ws = (char*)d_ws;
    unsigned char* xb4   = (unsigned char*)ws;
    unsigned char* WT4R  = (unsigned char*)(ws + WT4_OFF);
    float*         alpha = (float*)(ws + ALPHA_OFF);

    hipLaunchKernelGGL(prep_weights, dim3(OCH), dim3(256), 0, stream, w1, w2, WT4R, alpha);
    hipLaunchKernelGGL(binarize_kernel, dim3(NIMG * HPAD), dim3(256), 0, stream, x, xb4);
    hipLaunchKernelGGL(conv_kernel, dim3((M_TOT / 128) * 2), dim3(256), 0, stream,
                       xb4, WT4R, alpha, out);
}